// Round 20
// baseline (423.279 us; speedup 1.0000x reference)
//
#include <hip/hip_runtime.h>
#include <hip/hip_fp16.h>

#define K_DIM 4096
#define N_DIM 11008
#define NZ8   1376          // N_DIM/8
#define NKT   64            // K_DIM/64
#define NT_N  43            // N_DIM/256

typedef _Float16 f16x8 __attribute__((ext_vector_type(8)));
typedef float    f32x4 __attribute__((ext_vector_type(4)));

#define SB()    __builtin_amdgcn_sched_barrier(0)
#define VMW(N)  do { asm volatile("s_waitcnt vmcnt(" #N ")" ::: "memory"); SB(); } while (0)

// 1 int32 -> 8 fp16 dequant, (k,k+4)-interleaved order
__device__ __forceinline__ f16x8 dq8(unsigned q, __half2 scp, __half2 nzp)
{
    const unsigned mu = 0xE400E400u;
    const __half2 m1024 = *(const __half2*)&mu;
    union { __half2 h2[4]; f16x8 v; } p;
#pragma unroll
    for (int d = 0; d < 4; ++d) {
        unsigned t = ((q >> (4 * d)) & 0x000F000Fu) | 0x64006400u;
        p.h2[d] = __hfma2(__hadd2(*(const __half2*)&t, m1024), scp, nzp);
    }
    return p.v;
}

// ---- pre-pass: x f32 -> fp16 ws, layout [mt64][kt][kh][slot4][row64][16B]
// 16B chunk = 8 f16 of k = kt*64+kh*32+sl*8 in order (k0,k4,k1,k5,k2,k6,k3,k7)
__global__ __launch_bounds__(256)
void r20_xcvt(const float* __restrict__ x, __half* __restrict__ xh, int nchunks)
{
    int c = blockIdx.x * 256 + threadIdx.x;
    const int stride = gridDim.x * 256;
    for (; c < nchunks; c += stride) {
        const int row = c & 63;
        const int sl  = (c >> 6) & 3;
        const int kh  = (c >> 8) & 1;
        const int tl  = c >> 9;          // mt*64 + kt
        const int mt  = tl >> 6;
        const int kt  = tl & 63;
        const size_t gm = (size_t)mt * 64 + row;
        const int kb = kt * 64 + kh * 32 + sl * 8;
        const float4 f0 = *(const float4*)(x + gm * K_DIM + kb);
        const float4 f1 = *(const float4*)(x + gm * K_DIM + kb + 4);
        union { __half2 h2[4]; int4 v; } p;
        p.h2[0] = __floats2half2_rn(f0.x, f1.x);
        p.h2[1] = __floats2half2_rn(f0.y, f1.y);
        p.h2[2] = __floats2half2_rn(f0.z, f1.z);
        p.h2[3] = __floats2half2_rn(f0.w, f1.w);
        ((int4*)xh)[c] = p.v;
    }
}

// ---- issue helpers (64-bit-vaddr asm form, r13/r15-proven) ----
// 4 A-fragments (16B each) for one kh of the next tile -> register bank
#define ISSUE_A4(D, P) do { \
    asm volatile( \
        "global_load_dwordx4 %0, %4, off\n\t" \
        "global_load_dwordx4 %1, %4, off offset:256\n\t" \
        "global_load_dwordx4 %2, %4, off offset:512\n\t" \
        "global_load_dwordx4 %3, %4, off offset:768" \
        : "=&v"(D[0]), "=&v"(D[1]), "=&v"(D[2]), "=&v"(D[3]) \
        : "v"(P) : "memory"); \
} while (0)

// 4 q-dwords (one row, 4 col-groups) for one kh of the next tile
#define ISSUE_Q4(D0,D1,D2,D3, P) do { \
    asm volatile( \
        "global_load_dword %0, %4, off\n\t" \
        "global_load_dword %1, %4, off offset:64\n\t" \
        "global_load_dword %2, %4, off offset:128\n\t" \
        "global_load_dword %3, %4, off offset:192" \
        : "=&v"(D0), "=&v"(D1), "=&v"(D2), "=&v"(D3) \
        : "v"(P) : "memory"); \
} while (0)

// 4 scales + 4 qzero dwords for the NEXT group
#define ISSUE_SZ() do { \
    asm volatile( \
        "global_load_dword %0, %8, off\n\t" \
        "global_load_dword %1, %8, off offset:64\n\t" \
        "global_load_dword %2, %8, off offset:128\n\t" \
        "global_load_dword %3, %8, off offset:192\n\t" \
        "global_load_dword %4, %9, off\n\t" \
        "global_load_dword %5, %9, off offset:8\n\t" \
        "global_load_dword %6, %9, off offset:16\n\t" \
        "global_load_dword %7, %9, off offset:24" \
        : "=&v"(sS0), "=&v"(sS1), "=&v"(sS2), "=&v"(sS3), \
          "=&v"(sZ0), "=&v"(sZ1), "=&v"(sZ2), "=&v"(sZ3) \
        : "v"(sp), "v"(zp) : "memory"); \
    sp += N_DIM; zp += NZ8; \
} while (0)

#define DQ4(Q0,Q1,Q2,Q3) do { \
    bf[0] = dq8(Q0, scp0, nzp0); bf[1] = dq8(Q1, scp1, nzp1); \
    bf[2] = dq8(Q2, scp2, nzp2); bf[3] = dq8(Q3, scp3, nzp3); \
} while (0)

#define MFMA16(AF) do { \
    __builtin_amdgcn_s_setprio(1); \
    _Pragma("unroll") for (int m = 0; m < 4; ++m) \
        _Pragma("unroll") for (int n = 0; n < 4; ++n) \
            acc[m][n] = __builtin_amdgcn_mfma_f32_16x16x32_f16(AF[m], bf[n], acc[m][n], 0, 0, 0); \
    __builtin_amdgcn_s_setprio(0); \
    SB(); \
} while (0)

#define CVT_S() do { \
    const float _s0 = __uint_as_float(sS0), _s1 = __uint_as_float(sS1); \
    const float _s2 = __uint_as_float(sS2), _s3 = __uint_as_float(sS3); \
    const __half _h0 = __float2half_rn(_s0), _h1 = __float2half_rn(_s1); \
    const __half _h2 = __float2half_rn(_s2), _h3 = __float2half_rn(_s3); \
    scp0 = __half2(_h0, _h0); scp1 = __half2(_h1, _h1); \
    scp2 = __half2(_h2, _h2); scp3 = __half2(_h3, _h3); \
    const __half _n0 = __float2half_rn(-_s0 * (float)((sZ0 >> sh4) & 15u)); \
    const __half _n1 = __float2half_rn(-_s1 * (float)((sZ1 >> sh4) & 15u)); \
    const __half _n2 = __float2half_rn(-_s2 * (float)((sZ2 >> sh4) & 15u)); \
    const __half _n3 = __float2half_rn(-_s3 * (float)((sZ3 >> sh4) & 15u)); \
    nzp0 = __half2(_n0, _n0); nzp1 = __half2(_n1, _n1); \
    nzp2 = __half2(_n2, _n2); nzp3 = __half2(_n3, _n3); \
} while (0)

// ---- fused GEMM: wave-autonomous 64x64 tiles. NO LDS, NO barriers.
// A: direct global->reg from pre-cvt ws (4 waves/block share one m-strip ->
// L1 broadcast; XCD swizzle keeps the strip L2-hot). B: reg dequant (r15).
// Private per-wave counted-vmcnt ledger: A+q for (t+1,kh) issued at (t,kh);
// uniform VMW(8)/VMW(16), never 0 until the tail.
__global__ __launch_bounds__(256, 3)
void r20_gemm(const __half* __restrict__ xh,
              const int*   __restrict__ qweight,
              const int*   __restrict__ qzeros,
              const float* __restrict__ scales,
              const float* __restrict__ bias,
              float* __restrict__ out)
{
    const int tid  = threadIdx.x;
    const int lane = tid & 63;
    const int wid  = tid >> 6;           // 0..3

    int bid = blockIdx.x;                // XCD swizzle (2752 = 8*344)
    const int cpx = gridDim.x >> 3;
    bid = (bid & 7) * cpx + (bid >> 3);
    const int mt = bid / NT_N;           // m-strip (64 rows)
    const int nb = bid % NT_N;           // 256-col block

    const int frow = lane & 15, kb8 = lane >> 4;
    const int n0   = nb * 256 + wid * 64;
    const int ngl2 = n0 + frow;          // lane's base column
    const int sh4  = (ngl2 & 7) * 4;

    // A strip base for this lane (layout [mt][kt][kh][slot4][row64][16B])
    const char* ap = (const char*)xh + (size_t)mt * NKT * 8192
                   + kb8 * 1024 + frow * 16;

    const int*   qp0 = qweight + (size_t)kb8 * N_DIM + ngl2;        // kh0 row
    const int*   qp1 = qweight + (size_t)(4 + kb8) * N_DIM + ngl2;  // kh1 row
    const float* sp  = scales + (size_t)N_DIM + ngl2;               // group 1
    const int*   zp  = qzeros + (size_t)NZ8 + (ngl2 >> 3);          // group 1

    f32x4 acc[4][4];
#pragma unroll
    for (int m = 0; m < 4; ++m)
#pragma unroll
        for (int n = 0; n < 4; ++n)
            acc[m][n] = (f32x4){0.f, 0.f, 0.f, 0.f};
    f16x8 afA[4], afB[4], bf[4];
    __half2 scp0, scp1, scp2, scp3, nzp0, nzp1, nzp2, nzp3;
    unsigned q0, q1, q2, q3, q4, q5, q6, q7;
    unsigned sS0, sS1, sS2, sS3, sZ0, sZ1, sZ2, sZ3;

    // ---- prologue: group-0 scales plain-loaded & retired before the ledger
    sS0 = __float_as_uint(scales[ngl2]);
    sS1 = __float_as_uint(scales[ngl2 + 16]);
    sS2 = __float_as_uint(scales[ngl2 + 32]);
    sS3 = __float_as_uint(scales[ngl2 + 48]);
    sZ0 = (unsigned)qzeros[(ngl2 >> 3) + 0];
    sZ1 = (unsigned)qzeros[(ngl2 >> 3) + 2];
    sZ2 = (unsigned)qzeros[(ngl2 >> 3) + 4];
    sZ3 = (unsigned)qzeros[(ngl2 >> 3) + 6];
    asm volatile("" : "+v"(sS0), "+v"(sS1), "+v"(sS2), "+v"(sS3),
                      "+v"(sZ0), "+v"(sZ1), "+v"(sZ2), "+v"(sZ3));
    VMW(0);
    // ledger: A(0,kh0)4, q(0,kh0)4, A(0,kh1)4, q(0,kh1)4 -> 16 outstanding
    ISSUE_A4(afA, ap);
    ISSUE_Q4(q0, q1, q2, q3, qp0);
    ISSUE_A4(afB, ap + 4096);
    ISSUE_Q4(q4, q5, q6, q7, qp1);
    SB();
    ap += 8192; qp0 += 8 * N_DIM; qp1 += 8 * N_DIM;

    // ---- main loop: g = 0..30, tiles (2g, 2g+1); each (t,kh) issues (t+1,kh)
    for (int g = 0; g < 31; ++g) {
        // ===== even tile 2g, kh0 =====
        VMW(8);                          // retire [SZ(g),] A(t,kh0), q(t,kh0)
        CVT_S();                         // group g
        DQ4(q0, q1, q2, q3);
        MFMA16(afA);
        ISSUE_A4(afA, ap); SB();
        ISSUE_Q4(q0, q1, q2, q3, qp0); SB();
        // ===== even tile 2g, kh1 =====
        VMW(8);                          // retire A(t,kh1), q(t,kh1)
        DQ4(q4, q5, q6, q7);
        MFMA16(afB);
        ISSUE_A4(afB, ap + 4096); SB();
        ISSUE_Q4(q4, q5, q6, q7, qp1);
        ISSUE_SZ(); SB();                // group g+1 (g<=30 -> group<=31, OK)
        ap += 8192; qp0 += 8 * N_DIM; qp1 += 8 * N_DIM;
        // ===== odd tile 2g+1, kh0 =====
        VMW(16);                         // retire A,q(kh0); SZ+kh1' stay
        DQ4(q0, q1, q2, q3);
        MFMA16(afA);
        ISSUE_A4(afA, ap); SB();
        ISSUE_Q4(q0, q1, q2, q3, qp0); SB();
        // ===== odd tile 2g+1, kh1 =====
        VMW(16);                         // retire A,q(kh1)
        DQ4(q4, q5, q6, q7);
        MFMA16(afB);
        ISSUE_A4(afB, ap + 4096); SB();
        ISSUE_Q4(q4, q5, q6, q7, qp1); SB();
        ap += 8192; qp0 += 8 * N_DIM; qp1 += 8 * N_DIM;
    }

    // ---- tail: tile 62 (issues 63), tile 63 (no issues)
    VMW(8);
    CVT_S();                             // group 31
    DQ4(q0, q1, q2, q3);
    MFMA16(afA);
    ISSUE_A4(afA, ap); SB();
    ISSUE_Q4(q0, q1, q2, q3, qp0); SB();
    VMW(8);
    DQ4(q4, q5, q6, q7);
    MFMA16(afB);
    ISSUE_A4(afB, ap + 4096); SB();
    ISSUE_Q4(q4, q5, q6, q7, qp1); SB();
    // tile 63
    VMW(8);
    DQ4(q0, q1, q2, q3);
    MFMA16(afA);
    VMW(0);
    DQ4(q4, q5, q6, q7);
    MFMA16(afB);

    // ---- epilogue: C row=(lane>>4)*4+j, col=lane&15 (m89 layout)
#pragma unroll
    for (int n = 0; n < 4; ++n) {
        const int col = n0 + n * 16 + frow;
        const float bv = bias[col];
#pragma unroll
        for (int m = 0; m < 4; ++m) {
            const int row0 = mt * 64 + m * 16 + kb8 * 4;
#pragma unroll
            for (int j = 0; j < 4; ++j)
                out[(size_t)(row0 + j) * N_DIM + col] = acc[m][n][j] + bv;
        }
    }
}

// ---------------- fallback (ws too small): proven r8 kernel ----------------
typedef __bf16 bf16x8 __attribute__((ext_vector_type(8)));

__global__ __launch_bounds__(256, 2)
void r20_fb(const float* __restrict__ x,
            const int*   __restrict__ qweight,
            const int*   __restrict__ qzeros,
            const float* __restrict__ scales,
            const float* __restrict__ bias,
            float* __restrict__ out)
{
    __shared__ __align__(16) unsigned char Asm[128 * 64 * 2];
    __shared__ __align__(16) unsigned char Bsm[128 * 64 * 2];
    const int tid = threadIdx.x, lane = tid & 63, wv = tid >> 6;
    const int wr = (wv >> 1) * 64, wc = (wv & 1) * 64;
    int bid = blockIdx.x;
    const int cpx = gridDim.x >> 3;
    bid = (bid & 7) * cpx + (bid >> 3);
    const int bm0 = (bid / 86) * 128, bn0 = (bid % 86) * 128;
    const int ar = tid >> 4, ac4 = tid & 15;
    const float* xp = x + (size_t)(bm0 + ar) * K_DIM + ac4 * 4;
    unsigned char* aw = Asm + ar * 128 + ((ac4 * 8) ^ ((ar & 7) << 4));
    const int bnn = tid & 127, bk8q = tid >> 7, ngl = bn0 + bnn;
    const int* qwp = qweight + (size_t)bk8q * N_DIM + ngl;
    unsigned char* bw = Bsm + bnn * 128;
    const int bsw = bnn & 7;
    const int frow = lane & 15, kb8 = lane >> 4, fsw = frow & 7;
    f32x4 acc[4][4];
#pragma unroll
    for (int m = 0; m < 4; ++m)
#pragma unroll
        for (int n = 0; n < 4; ++n) acc[m][n] = (f32x4){0.f, 0.f, 0.f, 0.f};
    float sc = 0.f, nsz = 0.f;
    for (int kt = 0; kt < K_DIM / 64; ++kt) {
        const int k0 = kt * 64;
        if ((k0 & 127) == 0) {
            const int g = k0 >> 7;
            sc = scales[(size_t)g * N_DIM + ngl];
            const unsigned zq = (unsigned)qzeros[(size_t)g * NZ8 + (ngl >> 3)];
            nsz = -sc * (float)((zq >> ((ngl & 7) * 4)) & 15u);
        }
#pragma unroll
        for (int i = 0; i < 8; ++i) {
            const float4 v = *(const float4*)(xp + (size_t)i * 16 * K_DIM + k0);
            union { __bf16 h[4]; unsigned long long u; } p;
            p.h[0] = (__bf16)v.x; p.h[1] = (__bf16)v.y;
            p.h[2] = (__bf16)v.z; p.h[3] = (__bf16)v.w;
            *(unsigned long long*)(aw + i * 16 * 128) = p.u;
        }
#pragma unroll
        for (int i = 0; i < 4; ++i) {
            const int k8 = 2 * i + bk8q;
            const unsigned q = (unsigned)qwp[(size_t)(kt * 8 + 2 * i) * N_DIM];
            union { __bf16 h[8]; bf16x8 v8; } p;
#pragma unroll
            for (int j = 0; j < 8; ++j)
                p.h[j] = (__bf16)__builtin_fmaf(sc, (float)((q >> (4 * j)) & 15u), nsz);
            *(bf16x8*)(bw + ((k8 ^ bsw) << 4)) = p.v8;
        }
        __syncthreads();
#pragma unroll
        for (int kh = 0; kh < 2; ++kh) {
            const int ksl = (kh << 2) + kb8;
            bf16x8 a2[4], b2[4];
#pragma unroll
            for (int m = 0; m < 4; ++m)
                a2[m] = *(const bf16x8*)(Asm + (wr + m * 16 + frow) * 128 + ((ksl ^ fsw) << 4));
#pragma unroll
            for (int n = 0; n < 4; ++n)
                b2[n] = *(const bf16x8*)(Bsm + (wc + n * 16 + frow) * 128 + ((ksl ^ fsw) << 4));
#pragma unroll
            for (int m = 0; m < 4; ++m)
#pragma unroll
                for (int n = 0; n < 4; ++n)
                    acc[m][n] = __builtin_amdgcn_mfma_f32_16x16x32_bf16(a2[m], b2[n], acc[m][n], 0, 0, 0);
        }
        __syncthreads();
    }
    const int crow0 = (lane >> 4) << 2, ccol = lane & 15;
#pragma unroll
    for (int n = 0; n < 4; ++n) {
        const int col = bn0 + wc + n * 16 + ccol;
        const float bv = bias[col];
#pragma unroll
        for (int m = 0; m < 4; ++m) {
            const int row = bm0 + wr + m * 16 + crow0;
#pragma unroll
            for (int j = 0; j < 4; ++j)
                out[(size_t)(row + j) * N_DIM + col] = acc[m][n][j] + bv;
        }
    }
}

extern "C" void kernel_launch(void* const* d_in, const int* in_sizes, int n_in,
                              void* d_out, int out_size, void* d_ws, size_t ws_size,
                              hipStream_t stream)
{
    const float* x   = (const float*)d_in[0];
    const int*   qw  = (const int*)d_in[1];
    const int*   qz  = (const int*)d_in[2];
    const float* scl = (const float*)d_in[3];
    const float* bs  = (const float*)d_in[4];
    float* out = (float*)d_out;

    const int M = in_sizes[0] / K_DIM;               // 4096
    const size_t xh_bytes = (size_t)M * K_DIM * 2;   // 33.6 MB

    if (ws_size >= xh_bytes) {
        __half* xh = (__half*)d_ws;
        const int nchunks = M * K_DIM / 8;
        hipLaunchKernelGGL(r20_xcvt, dim3(2048), dim3(256), 0, stream, x, xh, nchunks);
        dim3 grid((M / 64) * NT_N);                  // 64*43 = 2752 (div by 8)
        hipLaunchKernelGGL(r20_gemm, grid, dim3(256), 0, stream,
                           xh, qw, qz, scl, bs, out);
    } else {
        dim3 grid((M / 128) * 86);                   // 2752
        hipLaunchKernelGGL(r20_fb, grid, dim3(256), 0, stream,
                           x, qw, qz, scl, bs, out);
    }
}